// Round 8
// baseline (73.033 us; speedup 1.0000x reference)
//
#include <hip/hip_runtime.h>
#include <hip/hip_bf16.h>
#include <cstddef>

// out[b,d,p] = sum_{t=0..62} filt[t] * act[b, (d+31-t) & 511, p]
// Banded circulant via mfma_f32_32x32x16_bf16.  Round 8: BARRIER-FREE.
// Each wave stages the full 192-row c-band it reads (own 128 + 64 halo)
// into the shared [hw][c] buffer; halo rows are double-written by the
// neighbor wave with bit-identical bf16 values (benign race). Every wave
// reads only rows it wrote itself -> no __syncthreads, only a wave-local
// lgkmcnt drain. Occupancy/layout/swizzle/MFMA identical to round 3.

#define NC    512
#define HW    3136          // 56*56
#define NT    32            // hw positions per block
#define NTILE (HW / NT)     // 98
#define NB    32
#define TPB   256

typedef __attribute__((ext_vector_type(8)))  short bf16x8;
typedef __attribute__((ext_vector_type(4)))  float f32x4;
typedef __attribute__((ext_vector_type(16))) float f32x16;

__device__ __forceinline__ short f2bf(float f) {
    union { __hip_bfloat16 h; short s; } u;
    u.h = __float2bfloat16(f);
    return u.s;
}

__device__ __forceinline__ int swzf(int hw) {
    return (((hw & 7) ^ (hw >> 3)) << 4);
}

__global__ __launch_bounds__(TPB, 4)
void toeplitz_nobar_kernel(const float* __restrict__ act,
                           const float* __restrict__ filt,
                           float* __restrict__ out) {
    // bf16 x-tile [hw][c]: byte = hw*1024 + ((c*2) ^ swzf(hw)).  32 KB.
    __shared__ __align__(16) unsigned short xs[NT * NC];

    const int tid  = threadIdx.x;
    const int wv   = tid >> 6;          // wave 0..3
    const int ln   = tid & 63;
    const int bx   = blockIdx.x;
    const int b    = bx / NTILE;
    const int tile = bx - b * NTILE;
    const int hw0  = tile * NT;

    // ---- A fragments: A_delta[r,k] = filt[delta + 31 + r - k] (0 outside)
    // lane: r = ln&31, k = (ln>>5)*8 + i.  delta(m) = 32 - 16*m, m=0..5
    const int r_a = ln & 31;
    const int k0  = (ln >> 5) * 8;
    bf16x8 af[6];
    #pragma unroll
    for (int m = 0; m < 6; ++m) {
        const int delta = 32 - 16 * m;
        #pragma unroll
        for (int i = 0; i < 8; ++i) {
            const int t = delta + 31 + r_a - (k0 + i);
            af[m][i] = (t >= 0 && t < 63) ? f2bf(filt[t]) : (short)0;
        }
    }

    // ---- wave-private stage: rows [wv*128-32, wv*128+160) (mod 512),
    // i.e. every row this wave's fragments will read.  Same [hw][c]
    // layout/swizzle as before; halo rows double-written (identical bits).
    {
        const float* gb = act + (size_t)b * NC * HW + hw0;
        const int g = ln >> 3;      // 0..7 row-pair group
        const int q = ln & 7;       // hw quad
        const int R0 = wv * 128 + 480;   // == wv*128 - 32 (mod 512)
        #pragma unroll
        for (int j = 0; j < 12; ++j) {
            const int r0 = (R0 + j * 16 + 2 * g) & (NC - 1);   // even
            const f32x4 a0 = *reinterpret_cast<const f32x4*>(gb + (size_t)r0 * HW + 4 * q);
            const f32x4 a1 = *reinterpret_cast<const f32x4*>(gb + (size_t)(r0 + 1) * HW + 4 * q);
            #pragma unroll
            for (int t4 = 0; t4 < 4; ++t4) {
                const int hw = 4 * q + t4;
                const unsigned int pk = (unsigned int)(unsigned short)f2bf(a0[t4])
                                      | ((unsigned int)(unsigned short)f2bf(a1[t4]) << 16);
                const int byte = hw * (NC * 2) + ((r0 * 2) ^ swzf(hw));
                *reinterpret_cast<unsigned int*>(reinterpret_cast<char*>(xs) + byte) = pk;
            }
        }
    }
    // wave-local: all my ds_writes complete; no inter-wave barrier needed
    asm volatile("s_waitcnt lgkmcnt(0)" ::: "memory");
    __builtin_amdgcn_sched_barrier(0);

    // ---- compute: wave wv owns d-tiles d0 = wv*128 + j*32, j=0..3.
    // B-frag for c-block c0: lane col = ln&31 (hw), k = (ln>>5)*8+i.
    const int hwl  = ln & 31;
    const int rowbyte = hwl * (NC * 2);
    const int swzv    = swzf(hwl);
    const int kb      = (ln >> 5) * 16;   // byte offset of k-half

    #define BFRAG(c0) (*reinterpret_cast<const bf16x8*>(                      \
        reinterpret_cast<const char*>(xs) +                                   \
        (rowbyte + (((((c0) & (NC - 1)) * 2) + kb) ^ swzv))))

    // 12 c-blocks per wave: c0 = wv*128 - 32 + 16*i, i=0..11 (each reused 3x)
    bf16x8 w[12];
    {
        const int cbase = wv * 128 - 32;
        #pragma unroll
        for (int i = 0; i < 12; ++i)
            w[i] = BFRAG(cbase + 16 * i);
    }

    float* ob = out + (size_t)b * NC * HW + hw0 + hwl;
    const int rhalf = (ln >> 5) * 4;

    #pragma unroll
    for (int j = 0; j < 4; ++j) {
        const int d0 = wv * 128 + j * 32;
        f32x16 acc;
        #pragma unroll
        for (int r = 0; r < 16; ++r) acc[r] = 0.0f;
        #pragma unroll
        for (int m = 0; m < 6; ++m)     // c0 = d0-32+16m, delta = 32-16m
            acc = __builtin_amdgcn_mfma_f32_32x32x16_bf16(af[m], w[2 * j + m], acc, 0, 0, 0);
        #pragma unroll
        for (int r = 0; r < 16; ++r) {
            const int row = d0 + (r & 3) + 8 * (r >> 2) + rhalf;
            __builtin_nontemporal_store(acc[r], ob + (size_t)row * HW);
        }
    }
    #undef BFRAG
}

extern "C" void kernel_launch(void* const* d_in, const int* in_sizes, int n_in,
                              void* d_out, int out_size, void* d_ws, size_t ws_size,
                              hipStream_t stream) {
    const float* act  = (const float*)d_in[0];   // (32, 512, 56, 56) f32
    const float* filt = (const float*)d_in[1];   // (1, 1, 63) f32
    float* out = (float*)d_out;                  // (32, 512, 56, 56) f32
    dim3 grid(NB * NTILE);    // 3136
    dim3 block(TPB);
    hipLaunchKernelGGL(toeplitz_nobar_kernel, grid, block, 0, stream,
                       act, filt, out);
}